// Round 3
// baseline (1369.270 us; speedup 1.0000x reference)
//
#include <hip/hip_runtime.h>

#define HW 65536
#define NBATCH 16
#define CCH 64
#define QKC 32

// workspace layout (float offsets)
#define OFF_WQT 0        // [64][32]  WqT folded (c-major rows of 32)
#define OFF_BQ  2048     // [32]
#define OFF_WKT 2080     // [64][32]
#define OFF_BK  4128     // [32]
#define OFF_WVT 4160     // [64][64]
#define OFF_BV  8256     // [64]
#define OFF_WO  8320     // [64][64]  row-major [c][j]
#define OFF_BO  12416    // [64]
#define OFF_F   12544    // [16][32][64]
#define OFF_MT  45312    // [16][32][64]  MT[n][i][c] = sum_j Wo'[c][j]*F[n][i][j]

#define BPN_A 128
#define BPN_B 128

__global__ __launch_bounds__(256) void k0_fold(
    const float* __restrict__ Wq, const float* __restrict__ bq,
    const float* __restrict__ qg, const float* __restrict__ qb,
    const float* __restrict__ qm, const float* __restrict__ qv,
    const float* __restrict__ Wk, const float* __restrict__ bk,
    const float* __restrict__ kg, const float* __restrict__ kb,
    const float* __restrict__ km, const float* __restrict__ kvar,
    const float* __restrict__ Wv, const float* __restrict__ bv,
    const float* __restrict__ vg, const float* __restrict__ vb,
    const float* __restrict__ vm, const float* __restrict__ vvar,
    const float* __restrict__ Wo, const float* __restrict__ bo,
    const float* __restrict__ og, const float* __restrict__ ob,
    const float* __restrict__ om, const float* __restrict__ ovar,
    float* __restrict__ ws)
{
    const int idx = blockIdx.x * 256 + threadIdx.x;
    if (idx < 2048) {                       // WqT[c][i]
        const int c = idx >> 5, i = idx & 31;
        const float s = qg[i] * rsqrtf(qv[i] + 1e-5f);
        ws[OFF_WQT + idx] = Wq[i * 64 + c] * s;
    } else if (idx < 2080) {
        const int i = idx - 2048;
        const float s = qg[i] * rsqrtf(qv[i] + 1e-5f);
        ws[OFF_BQ + i] = bq[i] * s + qb[i] - qm[i] * s;
    } else if (idx < 4128) {                // WkT[c][i]
        const int t = idx - 2080;
        const int c = t >> 5, i = t & 31;
        const float s = kg[i] * rsqrtf(kvar[i] + 1e-5f);
        ws[OFF_WKT + t] = Wk[i * 64 + c] * s;
    } else if (idx < 4160) {
        const int i = idx - 4128;
        const float s = kg[i] * rsqrtf(kvar[i] + 1e-5f);
        ws[OFF_BK + i] = bk[i] * s + kb[i] - km[i] * s;
    } else if (idx < 8256) {                // WvT[c][o]
        const int t = idx - 4160;
        const int c = t >> 6, o = t & 63;
        const float s = vg[o] * rsqrtf(vvar[o] + 1e-5f);
        ws[OFF_WVT + t] = Wv[o * 64 + c] * s;
    } else if (idx < 8320) {
        const int o = idx - 8256;
        const float s = vg[o] * rsqrtf(vvar[o] + 1e-5f);
        ws[OFF_BV + o] = bv[o] * s + vb[o] - vm[o] * s;
    } else if (idx < 12416) {               // Wo'[c][j]
        const int t = idx - 8320;
        const int c = t >> 6, j = t & 63;
        const float s = og[c] * rsqrtf(ovar[c] + 1e-5f);
        ws[OFF_WO + t] = Wo[c * 64 + j] * s;
    } else if (idx < 12480) {
        const int c = idx - 12416;
        const float s = og[c] * rsqrtf(ovar[c] + 1e-5f);
        ws[OFF_BO + c] = bo[c] * s + ob[c] - om[c] * s;
    } else if (idx < 12480 + 32768) {       // zero F (must happen every launch)
        ws[OFF_F + (idx - 12480)] = 0.0f;
    }
}

// Pass A: 256 threads/block, each thread owns 1 pixel per chunk.
// Weights are wave-uniform -> scalar/K$ path from global, not LDS.
// LDS stages 64 pixels of k/v per round (4 rounds per 256-px chunk).
__global__ __launch_bounds__(256, 4) void k1_passA(const float* __restrict__ x,
                                                   const float* __restrict__ wsc,
                                                   float* __restrict__ f)
{
    __shared__ float Kl[64 * 36];
    __shared__ float Vl[64 * 68];

    const int tid = threadIdx.x;
    const int n = blockIdx.x / BPN_A;
    const int bslot = blockIdx.x % BPN_A;

    const int half = tid >> 7;          // s2-range half
    const int t7 = tid & 127;
    const int i0 = (t7 & 7) * 4;        // k-row group (8 groups x 4)
    const int j0 = (t7 >> 3) * 4;       // v-col group (16 groups x 4)
    const int grp = tid >> 6;           // staging round owner (wave id)
    const int lane = tid & 63;

    const float4* wk4 = (const float4*)(wsc + OFF_WKT);   // [64][8]
    const float4* wv4 = (const float4*)(wsc + OFF_WVT);   // [64][16]

    float facc[4][4];
#pragma unroll
    for (int a = 0; a < 4; a++)
#pragma unroll
        for (int b = 0; b < 4; b++) facc[a][b] = 0.0f;

    const float* xn = x + (size_t)n * CCH * HW;

    for (int chunk = bslot; chunk < HW / 256; chunk += BPN_A) {
        const int s = chunk * 256 + tid;
        float kk[32], vv[64];
#pragma unroll
        for (int i = 0; i < 32; i++) kk[i] = wsc[OFF_BK + i];
#pragma unroll
        for (int o = 0; o < 64; o++) vv[o] = wsc[OFF_BV + o];

#pragma unroll 4
        for (int c = 0; c < 64; c++) {
            const float xc = xn[(size_t)c * HW + s];
#pragma unroll
            for (int i4 = 0; i4 < 8; i4++) {
                const float4 w = wk4[c * 8 + i4];
                kk[i4 * 4 + 0] += w.x * xc;
                kk[i4 * 4 + 1] += w.y * xc;
                kk[i4 * 4 + 2] += w.z * xc;
                kk[i4 * 4 + 3] += w.w * xc;
            }
#pragma unroll
            for (int o4 = 0; o4 < 16; o4++) {
                const float4 w = wv4[c * 16 + o4];
                vv[o4 * 4 + 0] += w.x * xc;
                vv[o4 * 4 + 1] += w.y * xc;
                vv[o4 * 4 + 2] += w.z * xc;
                vv[o4 * 4 + 3] += w.w * xc;
            }
        }

        float ssum = 0.0f;
#pragma unroll
        for (int i = 0; i < 32; i++) ssum += kk[i] * kk[i];
        const float inv = 1.0f / fmaxf(sqrtf(ssum), 1e-12f);
#pragma unroll
        for (int i = 0; i < 32; i++) kk[i] *= inv;
#pragma unroll
        for (int o = 0; o < 64; o++) vv[o] = fmaxf(vv[o], 0.0f);

#pragma unroll 1
        for (int r = 0; r < 4; ++r) {
            if (grp == r) {
#pragma unroll
                for (int i4 = 0; i4 < 8; i4++)
                    *(float4*)&Kl[lane * 36 + i4 * 4] =
                        make_float4(kk[i4 * 4], kk[i4 * 4 + 1], kk[i4 * 4 + 2], kk[i4 * 4 + 3]);
#pragma unroll
                for (int o4 = 0; o4 < 16; o4++)
                    *(float4*)&Vl[lane * 68 + o4 * 4] =
                        make_float4(vv[o4 * 4], vv[o4 * 4 + 1], vv[o4 * 4 + 2], vv[o4 * 4 + 3]);
            }
            __syncthreads();
            const int sbase = half * 32;
#pragma unroll 2
            for (int s2 = 0; s2 < 32; ++s2) {
                const float4 k4 = *(const float4*)&Kl[(sbase + s2) * 36 + i0];
                const float4 v4 = *(const float4*)&Vl[(sbase + s2) * 68 + j0];
                const float ka[4] = {k4.x, k4.y, k4.z, k4.w};
                const float va[4] = {v4.x, v4.y, v4.z, v4.w};
#pragma unroll
                for (int a = 0; a < 4; a++)
#pragma unroll
                    for (int b = 0; b < 4; b++) facc[a][b] += ka[a] * va[b];
            }
            __syncthreads();
        }
    }

    // merge the two s2-halves via LDS, then one atomic set per slot
    if (half == 1) {
#pragma unroll
        for (int a = 0; a < 4; a++)
#pragma unroll
            for (int b = 0; b < 4; b++) Kl[t7 * 16 + a * 4 + b] = facc[a][b];
    }
    __syncthreads();
    if (half == 0) {
        float* fn = f + n * (QKC * CCH);
#pragma unroll
        for (int a = 0; a < 4; a++)
#pragma unroll
            for (int b = 0; b < 4; b++)
                atomicAdd(&fn[(i0 + a) * 64 + (j0 + b)],
                          facc[a][b] + Kl[t7 * 16 + a * 4 + b]);
    }
}

// MT[n][i][c] = sum_j Wo'[c][j] * F[n][i][j]
__global__ __launch_bounds__(256) void k2_M(const float* __restrict__ wsc,
                                            float* __restrict__ ws)
{
    const int idx = blockIdx.x * 256 + threadIdx.x;
    if (idx >= NBATCH * QKC * CCH) return;
    const int n = idx / (QKC * CCH);
    const int r = idx % (QKC * CCH);
    const int i = r >> 6, c = r & 63;
    const float* wo = wsc + OFF_WO + c * 64;
    const float* fr = wsc + OFF_F + n * 2048 + i * 64;
    float acc = 0.0f;
#pragma unroll
    for (int j = 0; j < 64; j++) acc += wo[j] * fr[j];
    ws[OFF_MT + idx] = acc;
}

// Pass B: single x-stream. Accumulate q[32] and v0[64] together, normalize q,
// then apply MT^T q in two 32-channel halves to cap VGPR.
__global__ __launch_bounds__(256, 3) void k3_passB(const float* __restrict__ x,
                                                   const float* __restrict__ wsc,
                                                   float* __restrict__ out)
{
    const int tid = threadIdx.x;
    const int n = blockIdx.x / BPN_B;
    const int slot = blockIdx.x % BPN_B;

    const float4* wq4 = (const float4*)(wsc + OFF_WQT);           // [64][8]
    const float4* wv4 = (const float4*)(wsc + OFF_WVT);           // [64][16]
    const float4* mt4 = (const float4*)(wsc + OFF_MT + n * 2048); // [32][16]
    const float4* bo4 = (const float4*)(wsc + OFF_BO);
    const float4* bv4 = (const float4*)(wsc + OFF_BV);

    const float* xn = x + (size_t)n * CCH * HW;
    float* on = out + (size_t)n * CCH * HW;

    for (int it = 0; it < HW / (BPN_B * 256); it++) {
        const int s = slot * (HW / BPN_B) + it * 256 + tid;

        // ---- q and v0 in one x-stream ----
        float q[32];
#pragma unroll
        for (int i = 0; i < 32; i++) q[i] = wsc[OFF_BQ + i];
        float v0[64];
#pragma unroll
        for (int o4 = 0; o4 < 16; o4++) {
            const float4 b = bv4[o4];
            v0[o4 * 4 + 0] = b.x; v0[o4 * 4 + 1] = b.y;
            v0[o4 * 4 + 2] = b.z; v0[o4 * 4 + 3] = b.w;
        }
#pragma unroll 4
        for (int c = 0; c < 64; c++) {
            const float xc = xn[(size_t)c * HW + s];
#pragma unroll
            for (int i4 = 0; i4 < 8; i4++) {
                const float4 w = wq4[c * 8 + i4];
                q[i4 * 4 + 0] += w.x * xc;
                q[i4 * 4 + 1] += w.y * xc;
                q[i4 * 4 + 2] += w.z * xc;
                q[i4 * 4 + 3] += w.w * xc;
            }
#pragma unroll
            for (int o4 = 0; o4 < 16; o4++) {
                const float4 w = wv4[c * 16 + o4];
                v0[o4 * 4 + 0] += w.x * xc;
                v0[o4 * 4 + 1] += w.y * xc;
                v0[o4 * 4 + 2] += w.z * xc;
                v0[o4 * 4 + 3] += w.w * xc;
            }
        }
        float ssum = 0.0f;
#pragma unroll
        for (int i = 0; i < 32; i++) ssum += q[i] * q[i];
        const float inv = 1.0f / fmaxf(sqrtf(ssum), 1e-12f);
#pragma unroll
        for (int i = 0; i < 32; i++) q[i] *= inv;

        // ---- two 32-channel halves: oo = relu(MT^T q + bo); out = oo + v0 ----
#pragma unroll 1
        for (int h = 0; h < 2; h++) {
            float oo[32];
#pragma unroll
            for (int c4 = 0; c4 < 8; c4++) {
                const float4 b = bo4[h * 8 + c4];
                oo[c4 * 4 + 0] = b.x; oo[c4 * 4 + 1] = b.y;
                oo[c4 * 4 + 2] = b.z; oo[c4 * 4 + 3] = b.w;
            }
#pragma unroll 4
            for (int i = 0; i < 32; i++) {
                const float qi = q[i];
#pragma unroll
                for (int c4 = 0; c4 < 8; c4++) {
                    const float4 m = mt4[i * 16 + h * 8 + c4];
                    oo[c4 * 4 + 0] += m.x * qi;
                    oo[c4 * 4 + 1] += m.y * qi;
                    oo[c4 * 4 + 2] += m.z * qi;
                    oo[c4 * 4 + 3] += m.w * qi;
                }
            }
#pragma unroll
            for (int c = 0; c < 32; c++) {
                const int cc = h * 32 + c;
                on[(size_t)cc * HW + s] = fmaxf(oo[c], 0.0f) + v0[cc];
            }
        }
    }
}

extern "C" void kernel_launch(void* const* d_in, const int* in_sizes, int n_in,
                              void* d_out, int out_size, void* d_ws, size_t ws_size,
                              hipStream_t stream)
{
    const float* x    = (const float*)d_in[0];
    const float* Wq   = (const float*)d_in[1];
    const float* bq   = (const float*)d_in[2];
    const float* qg   = (const float*)d_in[3];
    const float* qb   = (const float*)d_in[4];
    const float* qm   = (const float*)d_in[5];
    const float* qv   = (const float*)d_in[6];
    const float* Wk   = (const float*)d_in[7];
    const float* bk   = (const float*)d_in[8];
    const float* kg   = (const float*)d_in[9];
    const float* kb   = (const float*)d_in[10];
    const float* km   = (const float*)d_in[11];
    const float* kvar = (const float*)d_in[12];
    const float* Wv   = (const float*)d_in[13];
    const float* bv   = (const float*)d_in[14];
    const float* vg   = (const float*)d_in[15];
    const float* vb   = (const float*)d_in[16];
    const float* vm   = (const float*)d_in[17];
    const float* vvar = (const float*)d_in[18];
    const float* Wo   = (const float*)d_in[19];
    const float* bo   = (const float*)d_in[20];
    const float* og   = (const float*)d_in[21];
    const float* ob   = (const float*)d_in[22];
    const float* om   = (const float*)d_in[23];
    const float* ovar = (const float*)d_in[24];

    float* ws  = (float*)d_ws;
    float* out = (float*)d_out;

    k0_fold<<<177, 256, 0, stream>>>(Wq, bq, qg, qb, qm, qv,
                                     Wk, bk, kg, kb, km, kvar,
                                     Wv, bv, vg, vb, vm, vvar,
                                     Wo, bo, og, ob, om, ovar, ws);

    k1_passA<<<NBATCH * BPN_A, 256, 0, stream>>>(x, (const float*)ws, ws + OFF_F);

    k2_M<<<128, 256, 0, stream>>>((const float*)ws, ws);

    k3_passB<<<NBATCH * BPN_B, 256, 0, stream>>>(x, (const float*)ws, out);
}

// Round 4
// 647.738 us; speedup vs baseline: 2.1139x; 2.1139x over previous
//
#include <hip/hip_runtime.h>

#define HW 65536
#define NBATCH 16
#define CCH 64
#define QKC 32

// workspace layout (float offsets)
#define OFF_WQT 0        // [64][32]  WqT folded (c-major rows of 32)
#define OFF_BQ  2048     // [32]
#define OFF_WKT 2080     // [64][32]
#define OFF_BK  4128     // [32]
#define OFF_WVT 4160     // [64][64]
#define OFF_BV  8256     // [64]
#define OFF_WO  8320     // [64][64]  row-major [c][j]
#define OFF_BO  12416    // [64]
#define OFF_F   12544    // [16][32][64]
#define OFF_MT  45312    // [16][32][64]  MT[n][i][c] = sum_j Wo'[c][j]*F[n][i][j]

#define BPN_A 128
#define BPN_B 128

__global__ __launch_bounds__(256) void k0_fold(
    const float* __restrict__ Wq, const float* __restrict__ bq,
    const float* __restrict__ qg, const float* __restrict__ qb,
    const float* __restrict__ qm, const float* __restrict__ qv,
    const float* __restrict__ Wk, const float* __restrict__ bk,
    const float* __restrict__ kg, const float* __restrict__ kb,
    const float* __restrict__ km, const float* __restrict__ kvar,
    const float* __restrict__ Wv, const float* __restrict__ bv,
    const float* __restrict__ vg, const float* __restrict__ vb,
    const float* __restrict__ vm, const float* __restrict__ vvar,
    const float* __restrict__ Wo, const float* __restrict__ bo,
    const float* __restrict__ og, const float* __restrict__ ob,
    const float* __restrict__ om, const float* __restrict__ ovar,
    float* __restrict__ ws)
{
    const int idx = blockIdx.x * 256 + threadIdx.x;
    if (idx < 2048) {                       // WqT[c][i]
        const int c = idx >> 5, i = idx & 31;
        const float s = qg[i] * rsqrtf(qv[i] + 1e-5f);
        ws[OFF_WQT + idx] = Wq[i * 64 + c] * s;
    } else if (idx < 2080) {
        const int i = idx - 2048;
        const float s = qg[i] * rsqrtf(qv[i] + 1e-5f);
        ws[OFF_BQ + i] = bq[i] * s + qb[i] - qm[i] * s;
    } else if (idx < 4128) {                // WkT[c][i]
        const int t = idx - 2080;
        const int c = t >> 5, i = t & 31;
        const float s = kg[i] * rsqrtf(kvar[i] + 1e-5f);
        ws[OFF_WKT + t] = Wk[i * 64 + c] * s;
    } else if (idx < 4160) {
        const int i = idx - 4128;
        const float s = kg[i] * rsqrtf(kvar[i] + 1e-5f);
        ws[OFF_BK + i] = bk[i] * s + kb[i] - km[i] * s;
    } else if (idx < 8256) {                // WvT[c][o]
        const int t = idx - 4160;
        const int c = t >> 6, o = t & 63;
        const float s = vg[o] * rsqrtf(vvar[o] + 1e-5f);
        ws[OFF_WVT + t] = Wv[o * 64 + c] * s;
    } else if (idx < 8320) {
        const int o = idx - 8256;
        const float s = vg[o] * rsqrtf(vvar[o] + 1e-5f);
        ws[OFF_BV + o] = bv[o] * s + vb[o] - vm[o] * s;
    } else if (idx < 12416) {               // Wo'[c][j]
        const int t = idx - 8320;
        const int c = t >> 6, j = t & 63;
        const float s = og[c] * rsqrtf(ovar[c] + 1e-5f);
        ws[OFF_WO + t] = Wo[c * 64 + j] * s;
    } else if (idx < 12480) {
        const int c = idx - 12416;
        const float s = og[c] * rsqrtf(ovar[c] + 1e-5f);
        ws[OFF_BO + c] = bo[c] * s + ob[c] - om[c] * s;
    } else if (idx < 12480 + 32768) {       // zero F (must happen every launch)
        ws[OFF_F + (idx - 12480)] = 0.0f;
    }
}

// Pass A: 256 threads/block, each thread owns 1 pixel per chunk.
// Weights are wave-uniform -> scalar/K$ path from global, not LDS.
// LDS stages 64 pixels of k/v per round (4 rounds per 256-px chunk).
// launch_bounds (256,2): do NOT squeeze VGPR below the 96 live accumulators —
// (256,4) forced 64 VGPR and caused 1.9 GB of scratch spills (round 3).
__global__ __launch_bounds__(256, 2) void k1_passA(const float* __restrict__ x,
                                                   const float* __restrict__ wsc,
                                                   float* __restrict__ f)
{
    __shared__ float Kl[64 * 36];
    __shared__ float Vl[64 * 68];

    const int tid = threadIdx.x;
    const int n = blockIdx.x / BPN_A;
    const int bslot = blockIdx.x % BPN_A;

    const int half = tid >> 7;          // s2-range half
    const int t7 = tid & 127;
    const int i0 = (t7 & 7) * 4;        // k-row group (8 groups x 4)
    const int j0 = (t7 >> 3) * 4;       // v-col group (16 groups x 4)
    const int grp = tid >> 6;           // staging round owner (wave id)
    const int lane = tid & 63;

    const float4* wk4 = (const float4*)(wsc + OFF_WKT);   // [64][8]
    const float4* wv4 = (const float4*)(wsc + OFF_WVT);   // [64][16]

    float facc[4][4];
#pragma unroll
    for (int a = 0; a < 4; a++)
#pragma unroll
        for (int b = 0; b < 4; b++) facc[a][b] = 0.0f;

    const float* xn = x + (size_t)n * CCH * HW;

    for (int chunk = bslot; chunk < HW / 256; chunk += BPN_A) {
        const int s = chunk * 256 + tid;
        float kk[32], vv[64];
#pragma unroll
        for (int i = 0; i < 32; i++) kk[i] = wsc[OFF_BK + i];
#pragma unroll
        for (int o = 0; o < 64; o++) vv[o] = wsc[OFF_BV + o];

#pragma unroll 4
        for (int c = 0; c < 64; c++) {
            const float xc = xn[(size_t)c * HW + s];
#pragma unroll
            for (int i4 = 0; i4 < 8; i4++) {
                const float4 w = wk4[c * 8 + i4];
                kk[i4 * 4 + 0] += w.x * xc;
                kk[i4 * 4 + 1] += w.y * xc;
                kk[i4 * 4 + 2] += w.z * xc;
                kk[i4 * 4 + 3] += w.w * xc;
            }
#pragma unroll
            for (int o4 = 0; o4 < 16; o4++) {
                const float4 w = wv4[c * 16 + o4];
                vv[o4 * 4 + 0] += w.x * xc;
                vv[o4 * 4 + 1] += w.y * xc;
                vv[o4 * 4 + 2] += w.z * xc;
                vv[o4 * 4 + 3] += w.w * xc;
            }
        }

        float ssum = 0.0f;
#pragma unroll
        for (int i = 0; i < 32; i++) ssum += kk[i] * kk[i];
        const float inv = 1.0f / fmaxf(sqrtf(ssum), 1e-12f);
#pragma unroll
        for (int i = 0; i < 32; i++) kk[i] *= inv;
#pragma unroll
        for (int o = 0; o < 64; o++) vv[o] = fmaxf(vv[o], 0.0f);

#pragma unroll 1
        for (int r = 0; r < 4; ++r) {
            if (grp == r) {
#pragma unroll
                for (int i4 = 0; i4 < 8; i4++)
                    *(float4*)&Kl[lane * 36 + i4 * 4] =
                        make_float4(kk[i4 * 4], kk[i4 * 4 + 1], kk[i4 * 4 + 2], kk[i4 * 4 + 3]);
#pragma unroll
                for (int o4 = 0; o4 < 16; o4++)
                    *(float4*)&Vl[lane * 68 + o4 * 4] =
                        make_float4(vv[o4 * 4], vv[o4 * 4 + 1], vv[o4 * 4 + 2], vv[o4 * 4 + 3]);
            }
            __syncthreads();
            const int sbase = half * 32;
#pragma unroll 2
            for (int s2 = 0; s2 < 32; ++s2) {
                const float4 k4 = *(const float4*)&Kl[(sbase + s2) * 36 + i0];
                const float4 v4 = *(const float4*)&Vl[(sbase + s2) * 68 + j0];
                const float ka[4] = {k4.x, k4.y, k4.z, k4.w};
                const float va[4] = {v4.x, v4.y, v4.z, v4.w};
#pragma unroll
                for (int a = 0; a < 4; a++)
#pragma unroll
                    for (int b = 0; b < 4; b++) facc[a][b] += ka[a] * va[b];
            }
            __syncthreads();
        }
    }

    // merge the two s2-halves via LDS, then one atomic set per slot
    if (half == 1) {
#pragma unroll
        for (int a = 0; a < 4; a++)
#pragma unroll
            for (int b = 0; b < 4; b++) Kl[t7 * 16 + a * 4 + b] = facc[a][b];
    }
    __syncthreads();
    if (half == 0) {
        float* fn = f + n * (QKC * CCH);
#pragma unroll
        for (int a = 0; a < 4; a++)
#pragma unroll
            for (int b = 0; b < 4; b++)
                atomicAdd(&fn[(i0 + a) * 64 + (j0 + b)],
                          facc[a][b] + Kl[t7 * 16 + a * 4 + b]);
    }
}

// MT[n][i][c] = sum_j Wo'[c][j] * F[n][i][j]
__global__ __launch_bounds__(256) void k2_M(const float* __restrict__ wsc,
                                            float* __restrict__ ws)
{
    const int idx = blockIdx.x * 256 + threadIdx.x;
    if (idx >= NBATCH * QKC * CCH) return;
    const int n = idx / (QKC * CCH);
    const int r = idx % (QKC * CCH);
    const int i = r >> 6, c = r & 63;
    const float* wo = wsc + OFF_WO + c * 64;
    const float* fr = wsc + OFF_F + n * 2048 + i * 64;
    float acc = 0.0f;
#pragma unroll
    for (int j = 0; j < 64; j++) acc += wo[j] * fr[j];
    ws[OFF_MT + idx] = acc;
}

// Pass B: single x-stream. Accumulate q[32] and v0[64] together, normalize q,
// then apply MT^T q in two 32-channel halves. (256,2): no register squeeze.
__global__ __launch_bounds__(256, 2) void k3_passB(const float* __restrict__ x,
                                                   const float* __restrict__ wsc,
                                                   float* __restrict__ out)
{
    const int tid = threadIdx.x;
    const int n = blockIdx.x / BPN_B;
    const int slot = blockIdx.x % BPN_B;

    const float4* wq4 = (const float4*)(wsc + OFF_WQT);           // [64][8]
    const float4* wv4 = (const float4*)(wsc + OFF_WVT);           // [64][16]
    const float4* mt4 = (const float4*)(wsc + OFF_MT + n * 2048); // [32][16]
    const float4* bo4 = (const float4*)(wsc + OFF_BO);
    const float4* bv4 = (const float4*)(wsc + OFF_BV);

    const float* xn = x + (size_t)n * CCH * HW;
    float* on = out + (size_t)n * CCH * HW;

    for (int it = 0; it < HW / (BPN_B * 256); it++) {
        const int s = slot * (HW / BPN_B) + it * 256 + tid;

        // ---- q and v0 in one x-stream ----
        float q[32];
#pragma unroll
        for (int i = 0; i < 32; i++) q[i] = wsc[OFF_BQ + i];
        float v0[64];
#pragma unroll
        for (int o4 = 0; o4 < 16; o4++) {
            const float4 b = bv4[o4];
            v0[o4 * 4 + 0] = b.x; v0[o4 * 4 + 1] = b.y;
            v0[o4 * 4 + 2] = b.z; v0[o4 * 4 + 3] = b.w;
        }
#pragma unroll 4
        for (int c = 0; c < 64; c++) {
            const float xc = xn[(size_t)c * HW + s];
#pragma unroll
            for (int i4 = 0; i4 < 8; i4++) {
                const float4 w = wq4[c * 8 + i4];
                q[i4 * 4 + 0] += w.x * xc;
                q[i4 * 4 + 1] += w.y * xc;
                q[i4 * 4 + 2] += w.z * xc;
                q[i4 * 4 + 3] += w.w * xc;
            }
#pragma unroll
            for (int o4 = 0; o4 < 16; o4++) {
                const float4 w = wv4[c * 16 + o4];
                v0[o4 * 4 + 0] += w.x * xc;
                v0[o4 * 4 + 1] += w.y * xc;
                v0[o4 * 4 + 2] += w.z * xc;
                v0[o4 * 4 + 3] += w.w * xc;
            }
        }
        float ssum = 0.0f;
#pragma unroll
        for (int i = 0; i < 32; i++) ssum += q[i] * q[i];
        const float inv = 1.0f / fmaxf(sqrtf(ssum), 1e-12f);
#pragma unroll
        for (int i = 0; i < 32; i++) q[i] *= inv;

        // ---- two 32-channel halves: oo = relu(MT^T q + bo); out = oo + v0 ----
#pragma unroll 1
        for (int h = 0; h < 2; h++) {
            float oo[32];
#pragma unroll
            for (int c4 = 0; c4 < 8; c4++) {
                const float4 b = bo4[h * 8 + c4];
                oo[c4 * 4 + 0] = b.x; oo[c4 * 4 + 1] = b.y;
                oo[c4 * 4 + 2] = b.z; oo[c4 * 4 + 3] = b.w;
            }
#pragma unroll 4
            for (int i = 0; i < 32; i++) {
                const float qi = q[i];
#pragma unroll
                for (int c4 = 0; c4 < 8; c4++) {
                    const float4 m = mt4[i * 16 + h * 8 + c4];
                    oo[c4 * 4 + 0] += m.x * qi;
                    oo[c4 * 4 + 1] += m.y * qi;
                    oo[c4 * 4 + 2] += m.z * qi;
                    oo[c4 * 4 + 3] += m.w * qi;
                }
            }
#pragma unroll
            for (int c = 0; c < 32; c++) {
                const int cc = h * 32 + c;
                on[(size_t)cc * HW + s] = fmaxf(oo[c], 0.0f) + v0[cc];
            }
        }
    }
}

extern "C" void kernel_launch(void* const* d_in, const int* in_sizes, int n_in,
                              void* d_out, int out_size, void* d_ws, size_t ws_size,
                              hipStream_t stream)
{
    const float* x    = (const float*)d_in[0];
    const float* Wq   = (const float*)d_in[1];
    const float* bq   = (const float*)d_in[2];
    const float* qg   = (const float*)d_in[3];
    const float* qb   = (const float*)d_in[4];
    const float* qm   = (const float*)d_in[5];
    const float* qv   = (const float*)d_in[6];
    const float* Wk   = (const float*)d_in[7];
    const float* bk   = (const float*)d_in[8];
    const float* kg   = (const float*)d_in[9];
    const float* kb   = (const float*)d_in[10];
    const float* km   = (const float*)d_in[11];
    const float* kvar = (const float*)d_in[12];
    const float* Wv   = (const float*)d_in[13];
    const float* bv   = (const float*)d_in[14];
    const float* vg   = (const float*)d_in[15];
    const float* vb   = (const float*)d_in[16];
    const float* vm   = (const float*)d_in[17];
    const float* vvar = (const float*)d_in[18];
    const float* Wo   = (const float*)d_in[19];
    const float* bo   = (const float*)d_in[20];
    const float* og   = (const float*)d_in[21];
    const float* ob   = (const float*)d_in[22];
    const float* om   = (const float*)d_in[23];
    const float* ovar = (const float*)d_in[24];

    float* ws  = (float*)d_ws;
    float* out = (float*)d_out;

    k0_fold<<<177, 256, 0, stream>>>(Wq, bq, qg, qb, qm, qv,
                                     Wk, bk, kg, kb, km, kvar,
                                     Wv, bv, vg, vb, vm, vvar,
                                     Wo, bo, og, ob, om, ovar, ws);

    k1_passA<<<NBATCH * BPN_A, 256, 0, stream>>>(x, (const float*)ws, ws + OFF_F);

    k2_M<<<128, 256, 0, stream>>>((const float*)ws, ws);

    k3_passB<<<NBATCH * BPN_B, 256, 0, stream>>>(x, (const float*)ws, out);
}

// Round 5
// 230.671 us; speedup vs baseline: 5.9360x; 2.8081x over previous
//
#include <hip/hip_runtime.h>

#define HW 65536
#define NBATCH 16
#define CCH 64
#define QKC 32

// workspace layout (float offsets)
#define OFF_WQT 0        // [64][32]  WqT folded (c-major rows of 32)
#define OFF_BQ  2048     // [32]
#define OFF_WKT 2080     // [64][32]
#define OFF_BK  4128     // [32]
#define OFF_WVT 4160     // [64][64]
#define OFF_BV  8256     // [64]
#define OFF_WO  8320     // [64][64]  row-major [c][j]
#define OFF_BO  12416    // [64]
#define OFF_F   12544    // [16][32][64]
#define OFF_MT  45312    // [16][32][64]  MT[n][i][c] = sum_j Wo'[c][j]*F[n][i][j]

#define BPN_A 128
#define BPN_B 128

typedef __attribute__((ext_vector_type(4))) float f32x4;
typedef __attribute__((ext_vector_type(8))) short bf16x8;
typedef __attribute__((ext_vector_type(4))) short bf16x4;

#define MFMA_P(a, b, c) __builtin_amdgcn_mfma_f32_16x16x32_bf16(a, b, c, 0, 0, 0)
#define MFMA_O(a, b, c) __builtin_amdgcn_mfma_f32_16x16x16bf16_1k(a, b, c, 0, 0, 0)

__device__ __forceinline__ short f2bf(float f) {
    union { float f; unsigned u; } v; v.f = f;
    unsigned r = v.u + 0x7FFFu + ((v.u >> 16) & 1u);   // round-to-nearest-even
    return (short)(r >> 16);
}

__global__ __launch_bounds__(256) void k0_fold(
    const float* __restrict__ Wq, const float* __restrict__ bq,
    const float* __restrict__ qg, const float* __restrict__ qb,
    const float* __restrict__ qm, const float* __restrict__ qv,
    const float* __restrict__ Wk, const float* __restrict__ bk,
    const float* __restrict__ kg, const float* __restrict__ kb,
    const float* __restrict__ km, const float* __restrict__ kvar,
    const float* __restrict__ Wv, const float* __restrict__ bv,
    const float* __restrict__ vg, const float* __restrict__ vb,
    const float* __restrict__ vm, const float* __restrict__ vvar,
    const float* __restrict__ Wo, const float* __restrict__ bo,
    const float* __restrict__ og, const float* __restrict__ ob,
    const float* __restrict__ om, const float* __restrict__ ovar,
    float* __restrict__ ws)
{
    const int idx = blockIdx.x * 256 + threadIdx.x;
    if (idx < 2048) {                       // WqT[c][i]
        const int c = idx >> 5, i = idx & 31;
        const float s = qg[i] * rsqrtf(qv[i] + 1e-5f);
        ws[OFF_WQT + idx] = Wq[i * 64 + c] * s;
    } else if (idx < 2080) {
        const int i = idx - 2048;
        const float s = qg[i] * rsqrtf(qv[i] + 1e-5f);
        ws[OFF_BQ + i] = bq[i] * s + qb[i] - qm[i] * s;
    } else if (idx < 4128) {                // WkT[c][i]
        const int t = idx - 2080;
        const int c = t >> 5, i = t & 31;
        const float s = kg[i] * rsqrtf(kvar[i] + 1e-5f);
        ws[OFF_WKT + t] = Wk[i * 64 + c] * s;
    } else if (idx < 4160) {
        const int i = idx - 4128;
        const float s = kg[i] * rsqrtf(kvar[i] + 1e-5f);
        ws[OFF_BK + i] = bk[i] * s + kb[i] - km[i] * s;
    } else if (idx < 8256) {                // WvT[c][o]
        const int t = idx - 4160;
        const int c = t >> 6, o = t & 63;
        const float s = vg[o] * rsqrtf(vvar[o] + 1e-5f);
        ws[OFF_WVT + t] = Wv[o * 64 + c] * s;
    } else if (idx < 8320) {
        const int o = idx - 8256;
        const float s = vg[o] * rsqrtf(vvar[o] + 1e-5f);
        ws[OFF_BV + o] = bv[o] * s + vb[o] - vm[o] * s;
    } else if (idx < 12416) {               // Wo'[c][j]
        const int t = idx - 8320;
        const int c = t >> 6, j = t & 63;
        const float s = og[c] * rsqrtf(ovar[c] + 1e-5f);
        ws[OFF_WO + t] = Wo[c * 64 + j] * s;
    } else if (idx < 12480) {
        const int c = idx - 12416;
        const float s = og[c] * rsqrtf(ovar[c] + 1e-5f);
        ws[OFF_BO + c] = bo[c] * s + ob[c] - om[c] * s;
    } else if (idx < 12480 + 32768) {       // zero F (must happen every launch)
        ws[OFF_F + (idx - 12480)] = 0.0f;
    }
}

// Pass A (MFMA): per wave, 16-pixel groups.
// Proj computed transposed: D[px][ch] via 16x16x32 (A = X^T, B = W^T).
// D layout (col=ch=lane&15, row=px=(lane>>4)*4+r) == A layout (m=kch,k=px)
// == B layout (n=vch,k=px) of the K=16 outer-product MFMA -> zero shuffles.
__global__ __launch_bounds__(256) void k1_passA(const float* __restrict__ x,
                                                const float* __restrict__ wsc,
                                                float* __restrict__ f)
{
    __shared__ float red[4 * 2048];

    const int tid = threadIdx.x;
    const int w = tid >> 6;
    const int lane = tid & 63;
    const int ln = lane & 15;
    const int lg = lane >> 4;

    const int n = blockIdx.x / BPN_A;
    const int bslot = blockIdx.x % BPN_A;
    const float* xn = x + (size_t)n * CCH * HW;

    // Weight B-frags (wave-uniform per lane): B[k=ch][n=och]
    bf16x8 wkf[2][2];
#pragma unroll
    for (int kk = 0; kk < 2; kk++)
#pragma unroll
        for (int t = 0; t < 2; t++) {
            bf16x8 a;
#pragma unroll
            for (int j = 0; j < 8; j++)
                a[j] = f2bf(wsc[OFF_WKT + (kk * 32 + lg * 8 + j) * 32 + t * 16 + ln]);
            wkf[kk][t] = a;
        }
    bf16x8 wvf[2][4];
#pragma unroll
    for (int kk = 0; kk < 2; kk++)
#pragma unroll
        for (int t = 0; t < 4; t++) {
            bf16x8 a;
#pragma unroll
            for (int j = 0; j < 8; j++)
                a[j] = f2bf(wsc[OFF_WVT + (kk * 32 + lg * 8 + j) * 64 + t * 16 + ln]);
            wvf[kk][t] = a;
        }
    float bkb[2], bvb[4];
#pragma unroll
    for (int t = 0; t < 2; t++) bkb[t] = wsc[OFF_BK + t * 16 + ln];
#pragma unroll
    for (int t = 0; t < 4; t++) bvb[t] = wsc[OFF_BV + t * 16 + ln];

    f32x4 facc[2][4];
#pragma unroll
    for (int t = 0; t < 2; t++)
#pragma unroll
        for (int vt = 0; vt < 4; vt++) facc[t][vt] = (f32x4){0.f, 0.f, 0.f, 0.f};

    for (int chunk = bslot; chunk < HW / 64; chunk += BPN_A) {
        const int sbase = chunk * 64 + w * 16;

        // x A-frags: A[m=px][k=ch]
        bf16x8 xa[2];
#pragma unroll
        for (int kk = 0; kk < 2; kk++) {
            const float* xp = xn + (kk * 32 + lg * 8) * HW + sbase + ln;
            bf16x8 a;
#pragma unroll
            for (int j = 0; j < 8; j++) a[j] = f2bf(xp[j * HW]);
            xa[kk] = a;
        }

        f32x4 dk[2], dv[4];
#pragma unroll
        for (int t = 0; t < 2; t++) dk[t] = (f32x4){bkb[t], bkb[t], bkb[t], bkb[t]};
#pragma unroll
        for (int t = 0; t < 4; t++) dv[t] = (f32x4){bvb[t], bvb[t], bvb[t], bvb[t]};
#pragma unroll
        for (int kk = 0; kk < 2; kk++) {
#pragma unroll
            for (int t = 0; t < 2; t++) dk[t] = MFMA_P(xa[kk], wkf[kk][t], dk[t]);
#pragma unroll
            for (int t = 0; t < 4; t++) dv[t] = MFMA_P(xa[kk], wvf[kk][t], dv[t]);
        }

        // per-pixel L2 norm of k: sum over kch = lanes 0..15 axis, per reg r
        float inv[4];
#pragma unroll
        for (int r = 0; r < 4; r++) {
            float s = dk[0][r] * dk[0][r] + dk[1][r] * dk[1][r];
            s += __shfl_xor(s, 1, 64);
            s += __shfl_xor(s, 2, 64);
            s += __shfl_xor(s, 4, 64);
            s += __shfl_xor(s, 8, 64);
            inv[r] = 1.0f / fmaxf(sqrtf(s), 1e-12f);
        }

        bf16x4 ka[2], vb[4];
#pragma unroll
        for (int t = 0; t < 2; t++)
#pragma unroll
            for (int r = 0; r < 4; r++) ka[t][r] = f2bf(dk[t][r] * inv[r]);
#pragma unroll
        for (int t = 0; t < 4; t++)
#pragma unroll
            for (int r = 0; r < 4; r++) vb[t][r] = f2bf(fmaxf(dv[t][r], 0.0f));

        // f[kch][vch] += k̂ · v̂^T  (K = 16 pixels)
#pragma unroll
        for (int t = 0; t < 2; t++)
#pragma unroll
            for (int vt = 0; vt < 4; vt++)
                facc[t][vt] = MFMA_O(ka[t], vb[vt], facc[t][vt]);
    }

    // merge 4 waves in LDS, then one atomicAdd per element
#pragma unroll
    for (int t = 0; t < 2; t++)
#pragma unroll
        for (int vt = 0; vt < 4; vt++)
#pragma unroll
            for (int r = 0; r < 4; r++)
                red[w * 2048 + (t * 16 + lg * 4 + r) * 64 + vt * 16 + ln] = facc[t][vt][r];
    __syncthreads();
    float* fn = f + n * (QKC * CCH);
    for (int idx = tid; idx < 2048; idx += 256)
        atomicAdd(&fn[idx], red[idx] + red[2048 + idx] + red[4096 + idx] + red[6144 + idx]);
}

// MT[n][i][c] = sum_j Wo'[c][j] * F[n][i][j]
__global__ __launch_bounds__(256) void k2_M(const float* __restrict__ wsc,
                                            float* __restrict__ ws)
{
    const int idx = blockIdx.x * 256 + threadIdx.x;
    if (idx >= NBATCH * QKC * CCH) return;
    const int n = idx / (QKC * CCH);
    const int r = idx % (QKC * CCH);
    const int i = r >> 6, c = r & 63;
    const float* wo = wsc + OFF_WO + c * 64;
    const float* fr = wsc + OFF_F + n * 2048 + i * 64;
    float acc = 0.0f;
#pragma unroll
    for (int j = 0; j < 64; j++) acc += wo[j] * fr[j];
    ws[OFF_MT + idx] = acc;
}

// Pass B (MFMA): q,v0 projections transposed; q̂ transposed via small LDS
// round-trip into the A-operand of y^T[px][och] = q̂^T · M^T; out = relu(y)+v0.
__global__ __launch_bounds__(256) void k3_passB(const float* __restrict__ x,
                                               const float* __restrict__ wsc,
                                               float* __restrict__ out)
{
    __shared__ float qt[4][16 * 36];   // per-wave q̂ transpose buffer (pad 36)

    const int tid = threadIdx.x;
    const int w = tid >> 6;
    const int lane = tid & 63;
    const int ln = lane & 15;
    const int lg = lane >> 4;

    const int n = blockIdx.x / BPN_B;
    const int slot = blockIdx.x % BPN_B;
    const float* xn = x + (size_t)n * CCH * HW;
    float* on = out + (size_t)n * CCH * HW;

    bf16x8 wqf[2][2];
#pragma unroll
    for (int kk = 0; kk < 2; kk++)
#pragma unroll
        for (int t = 0; t < 2; t++) {
            bf16x8 a;
#pragma unroll
            for (int j = 0; j < 8; j++)
                a[j] = f2bf(wsc[OFF_WQT + (kk * 32 + lg * 8 + j) * 32 + t * 16 + ln]);
            wqf[kk][t] = a;
        }
    bf16x8 wvf[2][4];
#pragma unroll
    for (int kk = 0; kk < 2; kk++)
#pragma unroll
        for (int t = 0; t < 4; t++) {
            bf16x8 a;
#pragma unroll
            for (int j = 0; j < 8; j++)
                a[j] = f2bf(wsc[OFF_WVT + (kk * 32 + lg * 8 + j) * 64 + t * 16 + ln]);
            wvf[kk][t] = a;
        }
    // M^T B-frags: B[k=qch][n=och], from fp32 MT[n][i][c]
    bf16x8 mtf[4];
#pragma unroll
    for (int t = 0; t < 4; t++) {
        bf16x8 a;
#pragma unroll
        for (int j = 0; j < 8; j++)
            a[j] = f2bf(wsc[OFF_MT + n * 2048 + (lg * 8 + j) * 64 + t * 16 + ln]);
        mtf[t] = a;
    }
    float bqb[2], bvb[4], bob[4];
#pragma unroll
    for (int t = 0; t < 2; t++) bqb[t] = wsc[OFF_BQ + t * 16 + ln];
#pragma unroll
    for (int t = 0; t < 4; t++) bvb[t] = wsc[OFF_BV + t * 16 + ln];
#pragma unroll
    for (int t = 0; t < 4; t++) bob[t] = wsc[OFF_BO + t * 16 + ln];

    for (int chunk = slot; chunk < HW / 64; chunk += BPN_B) {
        const int sbase = chunk * 64 + w * 16;

        bf16x8 xa[2];
#pragma unroll
        for (int kk = 0; kk < 2; kk++) {
            const float* xp = xn + (kk * 32 + lg * 8) * HW + sbase + ln;
            bf16x8 a;
#pragma unroll
            for (int j = 0; j < 8; j++) a[j] = f2bf(xp[j * HW]);
            xa[kk] = a;
        }

        f32x4 dq[2], dv0[4];
#pragma unroll
        for (int t = 0; t < 2; t++) dq[t] = (f32x4){bqb[t], bqb[t], bqb[t], bqb[t]};
#pragma unroll
        for (int t = 0; t < 4; t++) dv0[t] = (f32x4){bvb[t], bvb[t], bvb[t], bvb[t]};
#pragma unroll
        for (int kk = 0; kk < 2; kk++) {
#pragma unroll
            for (int t = 0; t < 2; t++) dq[t] = MFMA_P(xa[kk], wqf[kk][t], dq[t]);
#pragma unroll
            for (int t = 0; t < 4; t++) dv0[t] = MFMA_P(xa[kk], wvf[kk][t], dv0[t]);
        }

        float inv[4];
#pragma unroll
        for (int r = 0; r < 4; r++) {
            float s = dq[0][r] * dq[0][r] + dq[1][r] * dq[1][r];
            s += __shfl_xor(s, 1, 64);
            s += __shfl_xor(s, 2, 64);
            s += __shfl_xor(s, 4, 64);
            s += __shfl_xor(s, 8, 64);
            inv[r] = 1.0f / fmaxf(sqrtf(s), 1e-12f);
        }

        // transpose q̂ through LDS: write [px][qch], read A[m=px][k=qch]
#pragma unroll
        for (int t = 0; t < 2; t++)
#pragma unroll
            for (int r = 0; r < 4; r++)
                qt[w][(lg * 4 + r) * 36 + t * 16 + ln] = dq[t][r] * inv[r];
        __syncthreads();
        const f32x4 qlo = *(const f32x4*)&qt[w][ln * 36 + lg * 8];
        const f32x4 qhi = *(const f32x4*)&qt[w][ln * 36 + lg * 8 + 4];
        bf16x8 aq;
#pragma unroll
        for (int j = 0; j < 4; j++) { aq[j] = f2bf(qlo[j]); aq[4 + j] = f2bf(qhi[j]); }
        __syncthreads();

        f32x4 dy[4];
#pragma unroll
        for (int t = 0; t < 4; t++) dy[t] = (f32x4){bob[t], bob[t], bob[t], bob[t]};
#pragma unroll
        for (int t = 0; t < 4; t++) dy[t] = MFMA_P(aq, mtf[t], dy[t]);

        // out[och][px] = relu(y) + v0
#pragma unroll
        for (int t = 0; t < 4; t++) {
            float* op = on + (t * 16 + ln) * HW + sbase + lg * 4;
#pragma unroll
            for (int r = 0; r < 4; r++)
                op[r] = fmaxf(dy[t][r], 0.0f) + dv0[t][r];
        }
    }
}

extern "C" void kernel_launch(void* const* d_in, const int* in_sizes, int n_in,
                              void* d_out, int out_size, void* d_ws, size_t ws_size,
                              hipStream_t stream)
{
    const float* x    = (const float*)d_in[0];
    const float* Wq   = (const float*)d_in[1];
    const float* bq   = (const float*)d_in[2];
    const float* qg   = (const float*)d_in[3];
    const float* qb   = (const float*)d_in[4];
    const float* qm   = (const float*)d_in[5];
    const float* qv   = (const float*)d_in[6];
    const float* Wk   = (const float*)d_in[7];
    const float* bk   = (const float*)d_in[8];
    const float* kg   = (const float*)d_in[9];
    const float* kb   = (const float*)d_in[10];
    const float* km   = (const float*)d_in[11];
    const float* kvar = (const float*)d_in[12];
    const float* Wv   = (const float*)d_in[13];
    const float* bv   = (const float*)d_in[14];
    const float* vg   = (const float*)d_in[15];
    const float* vb   = (const float*)d_in[16];
    const float* vm   = (const float*)d_in[17];
    const float* vvar = (const float*)d_in[18];
    const float* Wo   = (const float*)d_in[19];
    const float* bo   = (const float*)d_in[20];
    const float* og   = (const float*)d_in[21];
    const float* ob   = (const float*)d_in[22];
    const float* om   = (const float*)d_in[23];
    const float* ovar = (const float*)d_in[24];

    float* ws  = (float*)d_ws;
    float* out = (float*)d_out;

    k0_fold<<<177, 256, 0, stream>>>(Wq, bq, qg, qb, qm, qv,
                                     Wk, bk, kg, kb, km, kvar,
                                     Wv, bv, vg, vb, vm, vvar,
                                     Wo, bo, og, ob, om, ovar, ws);

    k1_passA<<<NBATCH * BPN_A, 256, 0, stream>>>(x, (const float*)ws, ws + OFF_F);

    k2_M<<<128, 256, 0, stream>>>((const float*)ws, ws);

    k3_passB<<<NBATCH * BPN_B, 256, 0, stream>>>(x, (const float*)ws, out);
}

// Round 6
// 214.711 us; speedup vs baseline: 6.3773x; 1.0743x over previous
//
#include <hip/hip_runtime.h>

#define HW 65536
#define NBATCH 16
#define CCH 64
#define QKC 32

// workspace layout (float offsets)
#define OFF_WQT 0        // [64][32]  WqT folded (c-major rows of 32)
#define OFF_BQ  2048     // [32]
#define OFF_WKT 2080     // [64][32]
#define OFF_BK  4128     // [32]
#define OFF_WVT 4160     // [64][64]
#define OFF_BV  8256     // [64]
#define OFF_WO  8320     // [64][64]  row-major [c][j]
#define OFF_BO  12416    // [64]
#define OFF_F   12544    // [16][32][64]
#define OFF_MT  45312    // [16][32][64]  MT[n][i][c] = sum_j Wo'[c][j]*F[n][i][j]

#define BPN_A 128
#define BPN_B 128

typedef __attribute__((ext_vector_type(4))) float f32x4;
typedef __attribute__((ext_vector_type(8))) short bf16x8;
typedef __attribute__((ext_vector_type(4))) short bf16x4;

#define MFMA_P(a, b, c) __builtin_amdgcn_mfma_f32_16x16x32_bf16(a, b, c, 0, 0, 0)
#define MFMA_O(a, b, c) __builtin_amdgcn_mfma_f32_16x16x16bf16_1k(a, b, c, 0, 0, 0)

// float -> bf16 via hardware v_cvt_pk_bf16_f32 (m240: plain cast compiles to
// the HW instr; the old 4-op integer RNE was ~half of k1's VALU budget).
__device__ __forceinline__ short f2bf(float f) {
    __bf16 h = (__bf16)f;
    return __builtin_bit_cast(short, h);
}

__global__ __launch_bounds__(256) void k0_fold(
    const float* __restrict__ Wq, const float* __restrict__ bq,
    const float* __restrict__ qg, const float* __restrict__ qb,
    const float* __restrict__ qm, const float* __restrict__ qv,
    const float* __restrict__ Wk, const float* __restrict__ bk,
    const float* __restrict__ kg, const float* __restrict__ kb,
    const float* __restrict__ km, const float* __restrict__ kvar,
    const float* __restrict__ Wv, const float* __restrict__ bv,
    const float* __restrict__ vg, const float* __restrict__ vb,
    const float* __restrict__ vm, const float* __restrict__ vvar,
    const float* __restrict__ Wo, const float* __restrict__ bo,
    const float* __restrict__ og, const float* __restrict__ ob,
    const float* __restrict__ om, const float* __restrict__ ovar,
    float* __restrict__ ws)
{
    const int idx = blockIdx.x * 256 + threadIdx.x;
    if (idx < 2048) {                       // WqT[c][i]
        const int c = idx >> 5, i = idx & 31;
        const float s = qg[i] * rsqrtf(qv[i] + 1e-5f);
        ws[OFF_WQT + idx] = Wq[i * 64 + c] * s;
    } else if (idx < 2080) {
        const int i = idx - 2048;
        const float s = qg[i] * rsqrtf(qv[i] + 1e-5f);
        ws[OFF_BQ + i] = bq[i] * s + qb[i] - qm[i] * s;
    } else if (idx < 4128) {                // WkT[c][i]
        const int t = idx - 2080;
        const int c = t >> 5, i = t & 31;
        const float s = kg[i] * rsqrtf(kvar[i] + 1e-5f);
        ws[OFF_WKT + t] = Wk[i * 64 + c] * s;
    } else if (idx < 4160) {
        const int i = idx - 4128;
        const float s = kg[i] * rsqrtf(kvar[i] + 1e-5f);
        ws[OFF_BK + i] = bk[i] * s + kb[i] - km[i] * s;
    } else if (idx < 8256) {                // WvT[c][o]
        const int t = idx - 4160;
        const int c = t >> 6, o = t & 63;
        const float s = vg[o] * rsqrtf(vvar[o] + 1e-5f);
        ws[OFF_WVT + t] = Wv[o * 64 + c] * s;
    } else if (idx < 8320) {
        const int o = idx - 8256;
        const float s = vg[o] * rsqrtf(vvar[o] + 1e-5f);
        ws[OFF_BV + o] = bv[o] * s + vb[o] - vm[o] * s;
    } else if (idx < 12416) {               // Wo'[c][j]
        const int t = idx - 8320;
        const int c = t >> 6, j = t & 63;
        const float s = og[c] * rsqrtf(ovar[c] + 1e-5f);
        ws[OFF_WO + t] = Wo[c * 64 + j] * s;
    } else if (idx < 12480) {
        const int c = idx - 12416;
        const float s = og[c] * rsqrtf(ovar[c] + 1e-5f);
        ws[OFF_BO + c] = bo[c] * s + ob[c] - om[c] * s;
    } else if (idx < 12480 + 32768) {       // zero F (must happen every launch)
        ws[OFF_F + (idx - 12480)] = 0.0f;
    }
}

// Pass A (MFMA): per wave, 16-pixel groups.
// Proj computed transposed: D[px][ch] via 16x16x32 (A = X^T, B = W^T).
// D layout (col=ch=lane&15, row=px=(lane>>4)*4+r) == A layout (m=kch,k=px)
// == B layout (n=vch,k=px) of the K=16 outer-product MFMA -> zero shuffles.
__global__ __launch_bounds__(256) void k1_passA(const float* __restrict__ x,
                                                const float* __restrict__ wsc,
                                                float* __restrict__ f)
{
    __shared__ float red[4 * 2048];

    const int tid = threadIdx.x;
    const int w = tid >> 6;
    const int lane = tid & 63;
    const int ln = lane & 15;
    const int lg = lane >> 4;

    const int n = blockIdx.x / BPN_A;
    const int bslot = blockIdx.x % BPN_A;
    const float* xn = x + (size_t)n * CCH * HW;

    // Weight B-frags (wave-uniform per lane): B[k=ch][n=och]
    bf16x8 wkf[2][2];
#pragma unroll
    for (int kk = 0; kk < 2; kk++)
#pragma unroll
        for (int t = 0; t < 2; t++) {
            bf16x8 a;
#pragma unroll
            for (int j = 0; j < 8; j++)
                a[j] = f2bf(wsc[OFF_WKT + (kk * 32 + lg * 8 + j) * 32 + t * 16 + ln]);
            wkf[kk][t] = a;
        }
    bf16x8 wvf[2][4];
#pragma unroll
    for (int kk = 0; kk < 2; kk++)
#pragma unroll
        for (int t = 0; t < 4; t++) {
            bf16x8 a;
#pragma unroll
            for (int j = 0; j < 8; j++)
                a[j] = f2bf(wsc[OFF_WVT + (kk * 32 + lg * 8 + j) * 64 + t * 16 + ln]);
            wvf[kk][t] = a;
        }
    float bkb[2], bvb[4];
#pragma unroll
    for (int t = 0; t < 2; t++) bkb[t] = wsc[OFF_BK + t * 16 + ln];
#pragma unroll
    for (int t = 0; t < 4; t++) bvb[t] = wsc[OFF_BV + t * 16 + ln];

    f32x4 facc[2][4];
#pragma unroll
    for (int t = 0; t < 2; t++)
#pragma unroll
        for (int vt = 0; vt < 4; vt++) facc[t][vt] = (f32x4){0.f, 0.f, 0.f, 0.f};

    for (int chunk = bslot; chunk < HW / 64; chunk += BPN_A) {
        const int sbase = chunk * 64 + w * 16;

        // x A-frags: A[m=px][k=ch]
        bf16x8 xa[2];
#pragma unroll
        for (int kk = 0; kk < 2; kk++) {
            const float* xp = xn + (kk * 32 + lg * 8) * HW + sbase + ln;
            bf16x8 a;
#pragma unroll
            for (int j = 0; j < 8; j++) a[j] = f2bf(xp[j * HW]);
            xa[kk] = a;
        }

        f32x4 dk[2], dv[4];
#pragma unroll
        for (int t = 0; t < 2; t++) dk[t] = (f32x4){bkb[t], bkb[t], bkb[t], bkb[t]};
#pragma unroll
        for (int t = 0; t < 4; t++) dv[t] = (f32x4){bvb[t], bvb[t], bvb[t], bvb[t]};
#pragma unroll
        for (int kk = 0; kk < 2; kk++) {
#pragma unroll
            for (int t = 0; t < 2; t++) dk[t] = MFMA_P(xa[kk], wkf[kk][t], dk[t]);
#pragma unroll
            for (int t = 0; t < 4; t++) dv[t] = MFMA_P(xa[kk], wvf[kk][t], dv[t]);
        }

        // per-pixel L2 norm of k: sum over kch = lanes 0..15 axis, per reg r
        float inv[4];
#pragma unroll
        for (int r = 0; r < 4; r++) {
            float s = dk[0][r] * dk[0][r] + dk[1][r] * dk[1][r];
            s += __shfl_xor(s, 1, 64);
            s += __shfl_xor(s, 2, 64);
            s += __shfl_xor(s, 4, 64);
            s += __shfl_xor(s, 8, 64);
            inv[r] = 1.0f / fmaxf(sqrtf(s), 1e-12f);
        }

        bf16x4 ka[2], vb[4];
#pragma unroll
        for (int t = 0; t < 2; t++)
#pragma unroll
            for (int r = 0; r < 4; r++) ka[t][r] = f2bf(dk[t][r] * inv[r]);
#pragma unroll
        for (int t = 0; t < 4; t++)
#pragma unroll
            for (int r = 0; r < 4; r++) vb[t][r] = f2bf(fmaxf(dv[t][r], 0.0f));

        // f[kch][vch] += k̂ · v̂^T  (K = 16 pixels)
#pragma unroll
        for (int t = 0; t < 2; t++)
#pragma unroll
            for (int vt = 0; vt < 4; vt++)
                facc[t][vt] = MFMA_O(ka[t], vb[vt], facc[t][vt]);
    }

    // merge 4 waves in LDS, then one atomicAdd per element
#pragma unroll
    for (int t = 0; t < 2; t++)
#pragma unroll
        for (int vt = 0; vt < 4; vt++)
#pragma unroll
            for (int r = 0; r < 4; r++)
                red[w * 2048 + (t * 16 + lg * 4 + r) * 64 + vt * 16 + ln] = facc[t][vt][r];
    __syncthreads();
    float* fn = f + n * (QKC * CCH);
    for (int idx = tid; idx < 2048; idx += 256)
        atomicAdd(&fn[idx], red[idx] + red[2048 + idx] + red[4096 + idx] + red[6144 + idx]);
}

// MT[n][i][c] = sum_j Wo'[c][j] * F[n][i][j]
__global__ __launch_bounds__(256) void k2_M(const float* __restrict__ wsc,
                                            float* __restrict__ ws)
{
    const int idx = blockIdx.x * 256 + threadIdx.x;
    if (idx >= NBATCH * QKC * CCH) return;
    const int n = idx / (QKC * CCH);
    const int r = idx % (QKC * CCH);
    const int i = r >> 6, c = r & 63;
    const float* wo = wsc + OFF_WO + c * 64;
    const float* fr = wsc + OFF_F + n * 2048 + i * 64;
    float acc = 0.0f;
#pragma unroll
    for (int j = 0; j < 64; j++) acc += wo[j] * fr[j];
    ws[OFF_MT + idx] = acc;
}

// Pass B (MFMA): q,v0 projections transposed; q̂ transposed via a per-wave
// LDS buffer (wave-local ordering only -> NO __syncthreads needed);
// y^T[px][och] = q̂^T · M^T; out = relu(y)+v0 via nontemporal stores
// (keeps x resident in L3 for the tail of this pass and the next replay).
__global__ __launch_bounds__(256) void k3_passB(const float* __restrict__ x,
                                               const float* __restrict__ wsc,
                                               float* __restrict__ out)
{
    __shared__ float qt[4][16 * 36];   // per-wave q̂ transpose buffer (pad 36)

    const int tid = threadIdx.x;
    const int w = tid >> 6;
    const int lane = tid & 63;
    const int ln = lane & 15;
    const int lg = lane >> 4;

    const int n = blockIdx.x / BPN_B;
    const int slot = blockIdx.x % BPN_B;
    const float* xn = x + (size_t)n * CCH * HW;
    float* on = out + (size_t)n * CCH * HW;

    bf16x8 wqf[2][2];
#pragma unroll
    for (int kk = 0; kk < 2; kk++)
#pragma unroll
        for (int t = 0; t < 2; t++) {
            bf16x8 a;
#pragma unroll
            for (int j = 0; j < 8; j++)
                a[j] = f2bf(wsc[OFF_WQT + (kk * 32 + lg * 8 + j) * 32 + t * 16 + ln]);
            wqf[kk][t] = a;
        }
    bf16x8 wvf[2][4];
#pragma unroll
    for (int kk = 0; kk < 2; kk++)
#pragma unroll
        for (int t = 0; t < 4; t++) {
            bf16x8 a;
#pragma unroll
            for (int j = 0; j < 8; j++)
                a[j] = f2bf(wsc[OFF_WVT + (kk * 32 + lg * 8 + j) * 64 + t * 16 + ln]);
            wvf[kk][t] = a;
        }
    // M^T B-frags: B[k=qch][n=och], from fp32 MT[n][i][c]
    bf16x8 mtf[4];
#pragma unroll
    for (int t = 0; t < 4; t++) {
        bf16x8 a;
#pragma unroll
        for (int j = 0; j < 8; j++)
            a[j] = f2bf(wsc[OFF_MT + n * 2048 + (lg * 8 + j) * 64 + t * 16 + ln]);
        mtf[t] = a;
    }
    float bqb[2], bvb[4], bob[4];
#pragma unroll
    for (int t = 0; t < 2; t++) bqb[t] = wsc[OFF_BQ + t * 16 + ln];
#pragma unroll
    for (int t = 0; t < 4; t++) bvb[t] = wsc[OFF_BV + t * 16 + ln];
#pragma unroll
    for (int t = 0; t < 4; t++) bob[t] = wsc[OFF_BO + t * 16 + ln];

    for (int chunk = slot; chunk < HW / 64; chunk += BPN_B) {
        const int sbase = chunk * 64 + w * 16;

        bf16x8 xa[2];
#pragma unroll
        for (int kk = 0; kk < 2; kk++) {
            const float* xp = xn + (kk * 32 + lg * 8) * HW + sbase + ln;
            bf16x8 a;
#pragma unroll
            for (int j = 0; j < 8; j++) a[j] = f2bf(xp[j * HW]);
            xa[kk] = a;
        }

        f32x4 dq[2], dv0[4];
#pragma unroll
        for (int t = 0; t < 2; t++) dq[t] = (f32x4){bqb[t], bqb[t], bqb[t], bqb[t]};
#pragma unroll
        for (int t = 0; t < 4; t++) dv0[t] = (f32x4){bvb[t], bvb[t], bvb[t], bvb[t]};
#pragma unroll
        for (int kk = 0; kk < 2; kk++) {
#pragma unroll
            for (int t = 0; t < 2; t++) dq[t] = MFMA_P(xa[kk], wqf[kk][t], dq[t]);
#pragma unroll
            for (int t = 0; t < 4; t++) dv0[t] = MFMA_P(xa[kk], wvf[kk][t], dv0[t]);
        }

        float inv[4];
#pragma unroll
        for (int r = 0; r < 4; r++) {
            float s = dq[0][r] * dq[0][r] + dq[1][r] * dq[1][r];
            s += __shfl_xor(s, 1, 64);
            s += __shfl_xor(s, 2, 64);
            s += __shfl_xor(s, 4, 64);
            s += __shfl_xor(s, 8, 64);
            inv[r] = 1.0f / fmaxf(sqrtf(s), 1e-12f);
        }

        // transpose q̂ through the wave-private LDS slab: write [px][qch],
        // read A[m=px][k=qch]. Same wave writes & reads -> lgkmcnt ordering
        // (compiler-inserted) suffices; no block barrier.
#pragma unroll
        for (int t = 0; t < 2; t++)
#pragma unroll
            for (int r = 0; r < 4; r++)
                qt[w][(lg * 4 + r) * 36 + t * 16 + ln] = dq[t][r] * inv[r];
        const f32x4 qlo = *(const f32x4*)&qt[w][ln * 36 + lg * 8];
        const f32x4 qhi = *(const f32x4*)&qt[w][ln * 36 + lg * 8 + 4];
        bf16x8 aq;
#pragma unroll
        for (int j = 0; j < 4; j++) { aq[j] = f2bf(qlo[j]); aq[4 + j] = f2bf(qhi[j]); }

        f32x4 dy[4];
#pragma unroll
        for (int t = 0; t < 4; t++) dy[t] = (f32x4){bob[t], bob[t], bob[t], bob[t]};
#pragma unroll
        for (int t = 0; t < 4; t++) dy[t] = MFMA_P(aq, mtf[t], dy[t]);

        // out[och][px] = relu(y) + v0  (nontemporal: don't evict x from L3)
#pragma unroll
        for (int t = 0; t < 4; t++) {
            float* op = on + (size_t)(t * 16 + ln) * HW + sbase + lg * 4;
            f32x4 o4;
#pragma unroll
            for (int r = 0; r < 4; r++)
                o4[r] = fmaxf(dy[t][r], 0.0f) + dv0[t][r];
            __builtin_nontemporal_store(o4, (f32x4*)op);
        }
    }
}

extern "C" void kernel_launch(void* const* d_in, const int* in_sizes, int n_in,
                              void* d_out, int out_size, void* d_ws, size_t ws_size,
                              hipStream_t stream)
{
    const float* x    = (const float*)d_in[0];
    const float* Wq   = (const float*)d_in[1];
    const float* bq   = (const float*)d_in[2];
    const float* qg   = (const float*)d_in[3];
    const float* qb   = (const float*)d_in[4];
    const float* qm   = (const float*)d_in[5];
    const float* qv   = (const float*)d_in[6];
    const float* Wk   = (const float*)d_in[7];
    const float* bk   = (const float*)d_in[8];
    const float* kg   = (const float*)d_in[9];
    const float* kb   = (const float*)d_in[10];
    const float* km   = (const float*)d_in[11];
    const float* kvar = (const float*)d_in[12];
    const float* Wv   = (const float*)d_in[13];
    const float* bv   = (const float*)d_in[14];
    const float* vg   = (const float*)d_in[15];
    const float* vb   = (const float*)d_in[16];
    const float* vm   = (const float*)d_in[17];
    const float* vvar = (const float*)d_in[18];
    const float* Wo   = (const float*)d_in[19];
    const float* bo   = (const float*)d_in[20];
    const float* og   = (const float*)d_in[21];
    const float* ob   = (const float*)d_in[22];
    const float* om   = (const float*)d_in[23];
    const float* ovar = (const float*)d_in[24];

    float* ws  = (float*)d_ws;
    float* out = (float*)d_out;

    k0_fold<<<177, 256, 0, stream>>>(Wq, bq, qg, qb, qm, qv,
                                     Wk, bk, kg, kb, km, kvar,
                                     Wv, bv, vg, vb, vm, vvar,
                                     Wo, bo, og, ob, om, ovar, ws);

    k1_passA<<<NBATCH * BPN_A, 256, 0, stream>>>(x, (const float*)ws, ws + OFF_F);

    k2_M<<<128, 256, 0, stream>>>((const float*)ws, ws);

    k3_passB<<<NBATCH * BPN_B, 256, 0, stream>>>(x, (const float*)ws, out);
}

// Round 7
// 201.026 us; speedup vs baseline: 6.8114x; 1.0681x over previous
//
#include <hip/hip_runtime.h>

#define HW 65536
#define NBATCH 16
#define CCH 64
#define QKC 32

// workspace layout (float offsets)
#define OFF_WQT 0        // [64][32]  WqT folded (c-major rows of 32)
#define OFF_BQ  2048     // [32]
#define OFF_WKT 2080     // [64][32]
#define OFF_BK  4128     // [32]
#define OFF_WVT 4160     // [64][64]
#define OFF_BV  8256     // [64]
#define OFF_WO  8320     // [64][64]  row-major [c][j]
#define OFF_BO  12416    // [64]
#define OFF_F   12544    // [16][32][64]
#define OFF_MT  45312    // [16][32][64]  MT[n][i][c] = sum_j Wo'[c][j]*F[n][i][j]

#define BPN_A 128
#define BPN_B 128
#define NIT_A ((HW / 64) / BPN_A)   // 8 chunks per block, pass A
#define NIT_B ((HW / 64) / BPN_B)   // 8 chunks per block, pass B

typedef __attribute__((ext_vector_type(4))) float f32x4;
typedef __attribute__((ext_vector_type(8))) short bf16x8;
typedef __attribute__((ext_vector_type(4))) short bf16x4;

#define MFMA_P(a, b, c) __builtin_amdgcn_mfma_f32_16x16x32_bf16(a, b, c, 0, 0, 0)
#define MFMA_O(a, b, c) __builtin_amdgcn_mfma_f32_16x16x16bf16_1k(a, b, c, 0, 0, 0)

// float -> bf16 via hardware cvt (m240: plain cast compiles to the HW instr)
__device__ __forceinline__ short f2bf(float f) {
    __bf16 h = (__bf16)f;
    return __builtin_bit_cast(short, h);
}

__global__ __launch_bounds__(256) void k0_fold(
    const float* __restrict__ Wq, const float* __restrict__ bq,
    const float* __restrict__ qg, const float* __restrict__ qb,
    const float* __restrict__ qm, const float* __restrict__ qv,
    const float* __restrict__ Wk, const float* __restrict__ bk,
    const float* __restrict__ kg, const float* __restrict__ kb,
    const float* __restrict__ km, const float* __restrict__ kvar,
    const float* __restrict__ Wv, const float* __restrict__ bv,
    const float* __restrict__ vg, const float* __restrict__ vb,
    const float* __restrict__ vm, const float* __restrict__ vvar,
    const float* __restrict__ Wo, const float* __restrict__ bo,
    const float* __restrict__ og, const float* __restrict__ ob,
    const float* __restrict__ om, const float* __restrict__ ovar,
    float* __restrict__ ws)
{
    const int idx = blockIdx.x * 256 + threadIdx.x;
    if (idx < 2048) {                       // WqT[c][i]
        const int c = idx >> 5, i = idx & 31;
        const float s = qg[i] * rsqrtf(qv[i] + 1e-5f);
        ws[OFF_WQT + idx] = Wq[i * 64 + c] * s;
    } else if (idx < 2080) {
        const int i = idx - 2048;
        const float s = qg[i] * rsqrtf(qv[i] + 1e-5f);
        ws[OFF_BQ + i] = bq[i] * s + qb[i] - qm[i] * s;
    } else if (idx < 4128) {                // WkT[c][i]
        const int t = idx - 2080;
        const int c = t >> 5, i = t & 31;
        const float s = kg[i] * rsqrtf(kvar[i] + 1e-5f);
        ws[OFF_WKT + t] = Wk[i * 64 + c] * s;
    } else if (idx < 4160) {
        const int i = idx - 4128;
        const float s = kg[i] * rsqrtf(kvar[i] + 1e-5f);
        ws[OFF_BK + i] = bk[i] * s + kb[i] - km[i] * s;
    } else if (idx < 8256) {                // WvT[c][o]
        const int t = idx - 4160;
        const int c = t >> 6, o = t & 63;
        const float s = vg[o] * rsqrtf(vvar[o] + 1e-5f);
        ws[OFF_WVT + t] = Wv[o * 64 + c] * s;
    } else if (idx < 8320) {
        const int o = idx - 8256;
        const float s = vg[o] * rsqrtf(vvar[o] + 1e-5f);
        ws[OFF_BV + o] = bv[o] * s + vb[o] - vm[o] * s;
    } else if (idx < 12416) {               // Wo'[c][j]
        const int t = idx - 8320;
        const int c = t >> 6, j = t & 63;
        const float s = og[c] * rsqrtf(ovar[c] + 1e-5f);
        ws[OFF_WO + t] = Wo[c * 64 + j] * s;
    } else if (idx < 12480) {
        const int c = idx - 12416;
        const float s = og[c] * rsqrtf(ovar[c] + 1e-5f);
        ws[OFF_BO + c] = bo[c] * s + ob[c] - om[c] * s;
    } else if (idx < 12480 + 32768) {       // zero F (must happen every launch)
        ws[OFF_F + (idx - 12480)] = 0.0f;
    }
}

// Pass A (MFMA): per wave, 16-pixel groups, ASCENDING chunk order.
// x-tile double-buffered in fp32 regs: next chunk's 16 loads issued before
// current chunk's MFMA/norm/pack -> HBM latency hidden under compute.
__global__ __launch_bounds__(256) void k1_passA(const float* __restrict__ x,
                                                const float* __restrict__ wsc,
                                                float* __restrict__ f)
{
    __shared__ float red[4 * 2048];

    const int tid = threadIdx.x;
    const int w = tid >> 6;
    const int lane = tid & 63;
    const int ln = lane & 15;
    const int lg = lane >> 4;

    const int n = blockIdx.x / BPN_A;
    const int bslot = blockIdx.x % BPN_A;
    const float* xn = x + (size_t)n * CCH * HW;

    // Weight B-frags (wave-uniform per lane): B[k=ch][n=och]
    bf16x8 wkf[2][2];
#pragma unroll
    for (int kk = 0; kk < 2; kk++)
#pragma unroll
        for (int t = 0; t < 2; t++) {
            bf16x8 a;
#pragma unroll
            for (int j = 0; j < 8; j++)
                a[j] = f2bf(wsc[OFF_WKT + (kk * 32 + lg * 8 + j) * 32 + t * 16 + ln]);
            wkf[kk][t] = a;
        }
    bf16x8 wvf[2][4];
#pragma unroll
    for (int kk = 0; kk < 2; kk++)
#pragma unroll
        for (int t = 0; t < 4; t++) {
            bf16x8 a;
#pragma unroll
            for (int j = 0; j < 8; j++)
                a[j] = f2bf(wsc[OFF_WVT + (kk * 32 + lg * 8 + j) * 64 + t * 16 + ln]);
            wvf[kk][t] = a;
        }
    float bkb[2], bvb[4];
#pragma unroll
    for (int t = 0; t < 2; t++) bkb[t] = wsc[OFF_BK + t * 16 + ln];
#pragma unroll
    for (int t = 0; t < 4; t++) bvb[t] = wsc[OFF_BV + t * 16 + ln];

    f32x4 facc[2][4];
#pragma unroll
    for (int t = 0; t < 2; t++)
#pragma unroll
        for (int vt = 0; vt < 4; vt++) facc[t][vt] = (f32x4){0.f, 0.f, 0.f, 0.f};

    // prologue: load chunk 0's x-tile (fp32)
    float xf[16];
    {
        const int sbase = bslot * 64 + w * 16;
#pragma unroll
        for (int kk = 0; kk < 2; kk++) {
            const float* xp = xn + (size_t)(kk * 32 + lg * 8) * HW + sbase + ln;
#pragma unroll
            for (int j = 0; j < 8; j++) xf[kk * 8 + j] = xp[j * HW];
        }
    }

#pragma unroll
    for (int it = 0; it < NIT_A; ++it) {
        // prefetch next chunk's tile (stays in flight across the compute)
        float xf2[16];
        if (it + 1 < NIT_A) {
            const int sb2 = (bslot + (it + 1) * BPN_A) * 64 + w * 16;
#pragma unroll
            for (int kk = 0; kk < 2; kk++) {
                const float* xp = xn + (size_t)(kk * 32 + lg * 8) * HW + sb2 + ln;
#pragma unroll
                for (int j = 0; j < 8; j++) xf2[kk * 8 + j] = xp[j * HW];
            }
        }

        bf16x8 xa[2];
#pragma unroll
        for (int kk = 0; kk < 2; kk++)
#pragma unroll
            for (int j = 0; j < 8; j++) xa[kk][j] = f2bf(xf[kk * 8 + j]);

        f32x4 dk[2], dv[4];
#pragma unroll
        for (int t = 0; t < 2; t++) dk[t] = (f32x4){bkb[t], bkb[t], bkb[t], bkb[t]};
#pragma unroll
        for (int t = 0; t < 4; t++) dv[t] = (f32x4){bvb[t], bvb[t], bvb[t], bvb[t]};
#pragma unroll
        for (int kk = 0; kk < 2; kk++) {
#pragma unroll
            for (int t = 0; t < 2; t++) dk[t] = MFMA_P(xa[kk], wkf[kk][t], dk[t]);
#pragma unroll
            for (int t = 0; t < 4; t++) dv[t] = MFMA_P(xa[kk], wvf[kk][t], dv[t]);
        }

        // per-pixel L2 norm of k: sum over kch = lanes 0..15 axis, per reg r
        float inv[4];
#pragma unroll
        for (int r = 0; r < 4; r++) {
            float s = dk[0][r] * dk[0][r] + dk[1][r] * dk[1][r];
            s += __shfl_xor(s, 1, 64);
            s += __shfl_xor(s, 2, 64);
            s += __shfl_xor(s, 4, 64);
            s += __shfl_xor(s, 8, 64);
            inv[r] = 1.0f / fmaxf(sqrtf(s), 1e-12f);
        }

        bf16x4 ka[2], vb[4];
#pragma unroll
        for (int t = 0; t < 2; t++)
#pragma unroll
            for (int r = 0; r < 4; r++) ka[t][r] = f2bf(dk[t][r] * inv[r]);
#pragma unroll
        for (int t = 0; t < 4; t++)
#pragma unroll
            for (int r = 0; r < 4; r++) vb[t][r] = f2bf(fmaxf(dv[t][r], 0.0f));

        // f[kch][vch] += k̂ · v̂^T  (K = 16 pixels)
#pragma unroll
        for (int t = 0; t < 2; t++)
#pragma unroll
            for (int vt = 0; vt < 4; vt++)
                facc[t][vt] = MFMA_O(ka[t], vb[vt], facc[t][vt]);

        if (it + 1 < NIT_A) {
#pragma unroll
            for (int i = 0; i < 16; i++) xf[i] = xf2[i];
        }
    }

    // merge 4 waves in LDS, then one atomicAdd per element
#pragma unroll
    for (int t = 0; t < 2; t++)
#pragma unroll
        for (int vt = 0; vt < 4; vt++)
#pragma unroll
            for (int r = 0; r < 4; r++)
                red[w * 2048 + (t * 16 + lg * 4 + r) * 64 + vt * 16 + ln] = facc[t][vt][r];
    __syncthreads();
    float* fn = f + n * (QKC * CCH);
    for (int idx = tid; idx < 2048; idx += 256)
        atomicAdd(&fn[idx], red[idx] + red[2048 + idx] + red[4096 + idx] + red[6144 + idx]);
}

// MT[n][i][c] = sum_j Wo'[c][j] * F[n][i][j]
__global__ __launch_bounds__(256) void k2_M(const float* __restrict__ wsc,
                                            float* __restrict__ ws)
{
    const int idx = blockIdx.x * 256 + threadIdx.x;
    if (idx >= NBATCH * QKC * CCH) return;
    const int n = idx / (QKC * CCH);
    const int r = idx % (QKC * CCH);
    const int i = r >> 6, c = r & 63;
    const float* wo = wsc + OFF_WO + c * 64;
    const float* fr = wsc + OFF_F + n * 2048 + i * 64;
    float acc = 0.0f;
#pragma unroll
    for (int j = 0; j < 64; j++) acc += wo[j] * fr[j];
    ws[OFF_MT + idx] = acc;
}

// Pass B (MFMA): DESCENDING chunk order — k1 finishes with the x-tail hot in
// L3, so k3 consumes the tail first (and its low-chunk finish re-primes L3
// for the next replay's ascending k1). Same x double-buffering as k1.
__global__ __launch_bounds__(256) void k3_passB(const float* __restrict__ x,
                                               const float* __restrict__ wsc,
                                               float* __restrict__ out)
{
    __shared__ float qt[4][16 * 36];   // per-wave q̂ transpose buffer (pad 36)

    const int tid = threadIdx.x;
    const int w = tid >> 6;
    const int lane = tid & 63;
    const int ln = lane & 15;
    const int lg = lane >> 4;

    const int n = blockIdx.x / BPN_B;
    const int slot = blockIdx.x % BPN_B;
    const float* xn = x + (size_t)n * CCH * HW;
    float* on = out + (size_t)n * CCH * HW;

    bf16x8 wqf[2][2];
#pragma unroll
    for (int kk = 0; kk < 2; kk++)
#pragma unroll
        for (int t = 0; t < 2; t++) {
            bf16x8 a;
#pragma unroll
            for (int j = 0; j < 8; j++)
                a[j] = f2bf(wsc[OFF_WQT + (kk * 32 + lg * 8 + j) * 32 + t * 16 + ln]);
            wqf[kk][t] = a;
        }
    bf16x8 wvf[2][4];
#pragma unroll
    for (int kk = 0; kk < 2; kk++)
#pragma unroll
        for (int t = 0; t < 4; t++) {
            bf16x8 a;
#pragma unroll
            for (int j = 0; j < 8; j++)
                a[j] = f2bf(wsc[OFF_WVT + (kk * 32 + lg * 8 + j) * 64 + t * 16 + ln]);
            wvf[kk][t] = a;
        }
    // M^T B-frags: B[k=qch][n=och], from fp32 MT[n][i][c]
    bf16x8 mtf[4];
#pragma unroll
    for (int t = 0; t < 4; t++) {
        bf16x8 a;
#pragma unroll
        for (int j = 0; j < 8; j++)
            a[j] = f2bf(wsc[OFF_MT + n * 2048 + (lg * 8 + j) * 64 + t * 16 + ln]);
        mtf[t] = a;
    }
    float bqb[2], bvb[4], bob[4];
#pragma unroll
    for (int t = 0; t < 2; t++) bqb[t] = wsc[OFF_BQ + t * 16 + ln];
#pragma unroll
    for (int t = 0; t < 4; t++) bvb[t] = wsc[OFF_BV + t * 16 + ln];
#pragma unroll
    for (int t = 0; t < 4; t++) bob[t] = wsc[OFF_BO + t * 16 + ln];

    // descending chunk schedule: chunk(it) = (HW/64 - 1) - slot - it*BPN_B
    const int c0 = (HW / 64) - 1 - slot;

    float xf[16];
    {
        const int sbase = c0 * 64 + w * 16;
#pragma unroll
        for (int kk = 0; kk < 2; kk++) {
            const float* xp = xn + (size_t)(kk * 32 + lg * 8) * HW + sbase + ln;
#pragma unroll
            for (int j = 0; j < 8; j++) xf[kk * 8 + j] = xp[j * HW];
        }
    }

#pragma unroll
    for (int it = 0; it < NIT_B; ++it) {
        const int sbase = (c0 - it * BPN_B) * 64 + w * 16;

        float xf2[16];
        if (it + 1 < NIT_B) {
            const int sb2 = (c0 - (it + 1) * BPN_B) * 64 + w * 16;
#pragma unroll
            for (int kk = 0; kk < 2; kk++) {
                const float* xp = xn + (size_t)(kk * 32 + lg * 8) * HW + sb2 + ln;
#pragma unroll
                for (int j = 0; j < 8; j++) xf2[kk * 8 + j] = xp[j * HW];
            }
        }

        bf16x8 xa[2];
#pragma unroll
        for (int kk = 0; kk < 2; kk++)
#pragma unroll
            for (int j = 0; j < 8; j++) xa[kk][j] = f2bf(xf[kk * 8 + j]);

        f32x4 dq[2], dv0[4];
#pragma unroll
        for (int t = 0; t < 2; t++) dq[t] = (f32x4){bqb[t], bqb[t], bqb[t], bqb[t]};
#pragma unroll
        for (int t = 0; t < 4; t++) dv0[t] = (f32x4){bvb[t], bvb[t], bvb[t], bvb[t]};
#pragma unroll
        for (int kk = 0; kk < 2; kk++) {
#pragma unroll
            for (int t = 0; t < 2; t++) dq[t] = MFMA_P(xa[kk], wqf[kk][t], dq[t]);
#pragma unroll
            for (int t = 0; t < 4; t++) dv0[t] = MFMA_P(xa[kk], wvf[kk][t], dv0[t]);
        }

        float inv[4];
#pragma unroll
        for (int r = 0; r < 4; r++) {
            float s = dq[0][r] * dq[0][r] + dq[1][r] * dq[1][r];
            s += __shfl_xor(s, 1, 64);
            s += __shfl_xor(s, 2, 64);
            s += __shfl_xor(s, 4, 64);
            s += __shfl_xor(s, 8, 64);
            inv[r] = 1.0f / fmaxf(sqrtf(s), 1e-12f);
        }

        // transpose q̂ through the wave-private LDS slab (wave-local ordering
        // only -> no block barrier needed)
#pragma unroll
        for (int t = 0; t < 2; t++)
#pragma unroll
            for (int r = 0; r < 4; r++)
                qt[w][(lg * 4 + r) * 36 + t * 16 + ln] = dq[t][r] * inv[r];
        const f32x4 qlo = *(const f32x4*)&qt[w][ln * 36 + lg * 8];
        const f32x4 qhi = *(const f32x4*)&qt[w][ln * 36 + lg * 8 + 4];
        bf16x8 aq;
#pragma unroll
        for (int j = 0; j < 4; j++) { aq[j] = f2bf(qlo[j]); aq[4 + j] = f2bf(qhi[j]); }

        f32x4 dy[4];
#pragma unroll
        for (int t = 0; t < 4; t++) dy[t] = (f32x4){bob[t], bob[t], bob[t], bob[t]};
#pragma unroll
        for (int t = 0; t < 4; t++) dy[t] = MFMA_P(aq, mtf[t], dy[t]);

        // out[och][px] = relu(y) + v0  (nontemporal: don't evict x from L3)
#pragma unroll
        for (int t = 0; t < 4; t++) {
            float* op = on + (size_t)(t * 16 + ln) * HW + sbase + lg * 4;
            f32x4 o4;
#pragma unroll
            for (int r = 0; r < 4; r++)
                o4[r] = fmaxf(dy[t][r], 0.0f) + dv0[t][r];
            __builtin_nontemporal_store(o4, (f32x4*)op);
        }

        if (it + 1 < NIT_B) {
#pragma unroll
            for (int i = 0; i < 16; i++) xf[i] = xf2[i];
        }
    }
}

extern "C" void kernel_launch(void* const* d_in, const int* in_sizes, int n_in,
                              void* d_out, int out_size, void* d_ws, size_t ws_size,
                              hipStream_t stream)
{
    const float* x    = (const float*)d_in[0];
    const float* Wq   = (const float*)d_in[1];
    const float* bq   = (const float*)d_in[2];
    const float* qg   = (const float*)d_in[3];
    const float* qb   = (const float*)d_in[4];
    const float* qm   = (const float*)d_in[5];
    const float* qv   = (const float*)d_in[6];
    const float* Wk   = (const float*)d_in[7];
    const float* bk   = (const float*)d_in[8];
    const float* kg   = (const float*)d_in[9];
    const float* kb   = (const float*)d_in[10];
    const float* km   = (const float*)d_in[11];
    const float* kvar = (const float*)d_in[12];
    const float* Wv   = (const float*)d_in[13];
    const float* bv   = (const float*)d_in[14];
    const float* vg   = (const float*)d_in[15];
    const float* vb   = (const float*)d_in[16];
    const float* vm   = (const float*)d_in[17];
    const float* vvar = (const float*)d_in[18];
    const float* Wo   = (const float*)d_in[19];
    const float* bo   = (const float*)d_in[20];
    const float* og   = (const float*)d_in[21];
    const float* ob   = (const float*)d_in[22];
    const float* om   = (const float*)d_in[23];
    const float* ovar = (const float*)d_in[24];

    float* ws  = (float*)d_ws;
    float* out = (float*)d_out;

    k0_fold<<<177, 256, 0, stream>>>(Wq, bq, qg, qb, qm, qv,
                                     Wk, bk, kg, kb, km, kvar,
                                     Wv, bv, vg, vb, vm, vvar,
                                     Wo, bo, og, ob, om, ovar, ws);

    k1_passA<<<NBATCH * BPN_A, 256, 0, stream>>>(x, (const float*)ws, ws + OFF_F);

    k2_M<<<128, 256, 0, stream>>>((const float*)ws, ws);

    k3_passB<<<NBATCH * BPN_B, 256, 0, stream>>>(x, (const float*)ws, out);
}